// Round 1
// baseline (1080.557 us; speedup 1.0000x reference)
//
#include <hip/hip_runtime.h>
#include <hip/hip_bf16.h>

#define NNODE 50000
#define NEDGE 400000
#define NTOT  450000   // NEDGE + NNODE self-loops
#define FDIM  128
#define HEADS 8

static __device__ __forceinline__ float lrelu(float v) {
  return v > 0.f ? v : 0.2f * v;
}

// ---------------- CSR build ----------------

__global__ __launch_bounds__(256) void k_count(const int* __restrict__ ei, int* __restrict__ deg) {
  int t = blockIdx.x * 256 + threadIdx.x;
  if (t >= NTOT) return;
  int d = (t < NEDGE) ? ei[NEDGE + t] : (t - NEDGE);
  atomicAdd(&deg[d], 1);
}

__global__ __launch_bounds__(256) void k_scan(const int* __restrict__ deg, int* __restrict__ offs, int n) {
  __shared__ int buf[256];
  __shared__ int carry;
  if (threadIdx.x == 0) carry = 0;
  __syncthreads();
  for (int base = 0; base < n; base += 256) {
    int i = base + threadIdx.x;
    int v = (i < n) ? deg[i] : 0;
    buf[threadIdx.x] = v;
    __syncthreads();
    for (int off = 1; off < 256; off <<= 1) {
      int t = (threadIdx.x >= off) ? buf[threadIdx.x - off] : 0;
      __syncthreads();
      buf[threadIdx.x] += t;
      __syncthreads();
    }
    if (i < n) offs[i + 1] = carry + buf[threadIdx.x];
    __syncthreads();
    if (threadIdx.x == 255) carry += buf[255];
    __syncthreads();
  }
  if (threadIdx.x == 0) offs[0] = 0;
}

__global__ __launch_bounds__(256) void k_fill(const int* __restrict__ ei, const int* __restrict__ offs,
                                              int* __restrict__ cur, int* __restrict__ csrc,
                                              int* __restrict__ cdst) {
  int t = blockIdx.x * 256 + threadIdx.x;
  if (t >= NTOT) return;
  int s, d;
  if (t < NEDGE) { s = ei[t]; d = ei[NEDGE + t]; }
  else { s = t - NEDGE; d = s; }
  int pos = offs[d] + atomicAdd(&cur[d], 1);
  csrc[pos] = s;
  cdst[pos] = d;
}

// ---------------- dense GEMMs (fp32 vector) ----------------

// X: n x KD.  Wl, Wr: KD x OUTC each.  Computes xl = X@Wl, xr = X@Wr.
// Block: 256 threads, 8 rows, 256 columns of the combined 2*OUTC space.
template<int KD, int OUTC>
__global__ __launch_bounds__(256) void k_gemm_dual(const float* __restrict__ X,
                                                   const float* __restrict__ Wl,
                                                   const float* __restrict__ Wr,
                                                   float* __restrict__ xl, float* __restrict__ xr,
                                                   int n) {
  __shared__ float xs[KD * 8];   // transposed: xs[k*8 + r]
  int row0 = blockIdx.x * 8;
  for (int t = threadIdx.x; t < 8 * KD; t += 256) {
    int r = t / KD, k = t % KD;
    int row = row0 + r;
    xs[k * 8 + r] = (row < n) ? X[(size_t)row * KD + k] : 0.f;
  }
  __syncthreads();
  int colg = blockIdx.y * 256 + threadIdx.x;   // [0, 2*OUTC)
  const float* W = (colg < OUTC) ? Wl : Wr;
  int col = (colg < OUTC) ? colg : colg - OUTC;
  float acc[8] = {0.f, 0.f, 0.f, 0.f, 0.f, 0.f, 0.f, 0.f};
  for (int k = 0; k < KD; ++k) {
    float w = W[k * OUTC + col];
    float4 a0 = *(const float4*)&xs[k * 8 + 0];
    float4 a1 = *(const float4*)&xs[k * 8 + 4];
    acc[0] += a0.x * w; acc[1] += a0.y * w; acc[2] += a0.z * w; acc[3] += a0.w * w;
    acc[4] += a1.x * w; acc[5] += a1.y * w; acc[6] += a1.z * w; acc[7] += a1.w * w;
  }
  float* OUT = (colg < OUTC) ? xl : xr;
  for (int r = 0; r < 8; ++r) {
    int row = row0 + r;
    if (row < n) OUT[(size_t)row * OUTC + col] = acc[r];
  }
}

// residual = X(128) @ W(128x32) + b.  Block: 8 rows x 32 cols.
__global__ __launch_bounds__(256) void k_residual(const float* __restrict__ X,
                                                  const float* __restrict__ W,
                                                  const float* __restrict__ b,
                                                  float* __restrict__ out, int n) {
  __shared__ float xs[8 * 128];
  int row0 = blockIdx.x * 8;
  for (int t = threadIdx.x; t < 8 * 128; t += 256) {
    int r = t >> 7, k = t & 127;
    xs[t] = (row0 + r < n) ? X[(size_t)(row0 + r) * 128 + k] : 0.f;
  }
  __syncthreads();
  int r = threadIdx.x >> 5, c = threadIdx.x & 31;
  float acc = 0.f;
  for (int k = 0; k < 128; ++k) acc += xs[r * 128 + k] * W[k * 32 + c];
  if (row0 + r < n) out[(size_t)(row0 + r) * 32 + c] = acc + b[c];
}

// ---------------- edge scores ----------------

// D = H*CH total channels (512 or 256); VEC = D/64 channels per lane.
// One wave per CSR slot; per-head reduce over 8-lane groups.
template<int D, int VEC>
__global__ __launch_bounds__(256) void k_score(const float* __restrict__ xl,
                                               const float* __restrict__ xr,
                                               const float* __restrict__ att,
                                               const int* __restrict__ csrc,
                                               const int* __restrict__ cdst,
                                               float* __restrict__ ebuf) {
  int slot = blockIdx.x * 4 + (threadIdx.x >> 6);
  int lane = threadIdx.x & 63;
  if (slot >= NTOT) return;
  int s = csrc[slot], d = cdst[slot];
  const float* pl = xl + (size_t)s * D + lane * VEC;
  const float* pr = xr + (size_t)d * D + lane * VEC;
  const float* pa = att + lane * VEC;
  float acc = 0.f;
#pragma unroll
  for (int v = 0; v < VEC; v += 4) {
    float4 a = *(const float4*)(pl + v);
    float4 bb = *(const float4*)(pr + v);
    float4 w = *(const float4*)(pa + v);
    acc += lrelu(a.x + bb.x) * w.x;
    acc += lrelu(a.y + bb.y) * w.y;
    acc += lrelu(a.z + bb.z) * w.z;
    acc += lrelu(a.w + bb.w) * w.w;
  }
  acc += __shfl_xor(acc, 1);
  acc += __shfl_xor(acc, 2);
  acc += __shfl_xor(acc, 4);
  if ((lane & 7) == 0) ebuf[(size_t)slot * 8 + (lane >> 3)] = acc;
}

// ---------------- per-node softmax + aggregate ----------------

// Layer 1: D=512 (8 heads x 64). lane = channel c. Output: mean over heads + bias, ReLU.
__global__ __launch_bounds__(256) void k_agg1(const float* __restrict__ xl,
                                              const float* __restrict__ ebuf,
                                              const int* __restrict__ csrc,
                                              const int* __restrict__ offs,
                                              const float* __restrict__ bias,
                                              float* __restrict__ out) {
  int node = blockIdx.x * 4 + (threadIdx.x >> 6);
  int lane = threadIdx.x & 63;
  if (node >= NNODE) return;
  int beg = offs[node], end = offs[node + 1];
  float m[8];
#pragma unroll
  for (int h = 0; h < 8; ++h) m[h] = -1e30f;
  for (int i = beg; i < end; ++i) {
#pragma unroll
    for (int h = 0; h < 8; ++h) m[h] = fmaxf(m[h], ebuf[(size_t)i * 8 + h]);
  }
  float sden[8] = {0,0,0,0,0,0,0,0}, acc[8] = {0,0,0,0,0,0,0,0};
  for (int i = beg; i < end; ++i) {
    int s = csrc[i];
    const float* p = xl + (size_t)s * 512;
#pragma unroll
    for (int h = 0; h < 8; ++h) {
      float w = __expf(ebuf[(size_t)i * 8 + h] - m[h]);
      sden[h] += w;
      acc[h] += w * p[h * 64 + lane];
    }
  }
  float o = 0.f;
#pragma unroll
  for (int h = 0; h < 8; ++h) o += acc[h] / sden[h];
  o = o * 0.125f + bias[lane];
  o = fmaxf(o, 0.f);
  out[(size_t)node * 64 + lane] = o;
}

// Layer 2: D=256 (8 heads x 32). lanes 0-31: heads 0-3, lanes 32-63: heads 4-7.
__global__ __launch_bounds__(256) void k_agg2(const float* __restrict__ xl,
                                              const float* __restrict__ ebuf,
                                              const int* __restrict__ csrc,
                                              const int* __restrict__ offs,
                                              const float* __restrict__ bias,
                                              const float* __restrict__ resid,
                                              float* __restrict__ out) {
  int node = blockIdx.x * 4 + (threadIdx.x >> 6);
  int lane = threadIdx.x & 63;
  if (node >= NNODE) return;
  int half = lane >> 5, c = lane & 31;
  int beg = offs[node], end = offs[node + 1];
  float m[4];
#pragma unroll
  for (int j = 0; j < 4; ++j) m[j] = -1e30f;
  for (int i = beg; i < end; ++i) {
#pragma unroll
    for (int j = 0; j < 4; ++j) m[j] = fmaxf(m[j], ebuf[(size_t)i * 8 + half * 4 + j]);
  }
  float sden[4] = {0,0,0,0}, acc[4] = {0,0,0,0};
  for (int i = beg; i < end; ++i) {
    int s = csrc[i];
    const float* p = xl + (size_t)s * 256;
#pragma unroll
    for (int j = 0; j < 4; ++j) {
      float w = __expf(ebuf[(size_t)i * 8 + half * 4 + j] - m[j]);
      sden[j] += w;
      acc[j] += w * p[(half * 4 + j) * 32 + c];
    }
  }
  float o = 0.f;
#pragma unroll
  for (int j = 0; j < 4; ++j) o += acc[j] / sden[j];
  o += __shfl_xor(o, 32);
  o = o * 0.125f + bias[c] + resid[(size_t)node * 32 + c];
  if (half == 0) out[(size_t)node * 32 + c] = o;
}

// ---------------- launch ----------------

extern "C" void kernel_launch(void* const* d_in, const int* in_sizes, int n_in,
                              void* d_out, int out_size, void* d_ws, size_t ws_size,
                              hipStream_t stream) {
  const float* x      = (const float*)d_in[0];
  const int*   ei     = (const int*)d_in[1];
  const float* lin1_w = (const float*)d_in[3];
  const float* lin1_b = (const float*)d_in[4];
  const float* wl1    = (const float*)d_in[5];
  const float* wr1    = (const float*)d_in[6];
  const float* att1   = (const float*)d_in[7];
  const float* b1     = (const float*)d_in[8];
  const float* wl2    = (const float*)d_in[9];
  const float* wr2    = (const float*)d_in[10];
  const float* att2   = (const float*)d_in[11];
  const float* b2     = (const float*)d_in[12];
  float* out = (float*)d_out;

  char* p = (char*)d_ws;
  auto alloc = [&](size_t bytes) {
    char* r = p;
    p += (bytes + 255) & ~size_t(255);
    return r;
  };
  int*   offs  = (int*)alloc((NNODE + 1) * 4);
  int*   deg   = (int*)alloc(NNODE * 4);
  int*   cur   = (int*)alloc(NNODE * 4);
  int*   csrc  = (int*)alloc((size_t)NTOT * 4);
  int*   cdst  = (int*)alloc((size_t)NTOT * 4);
  float* ebuf  = (float*)alloc((size_t)NTOT * 8 * 4);
  float* xl    = (float*)alloc((size_t)NNODE * 512 * 4);   // reused as xl2 (N*256)
  float* xr    = (float*)alloc((size_t)NNODE * 512 * 4);   // reused as xr2 (N*256)
  float* h1    = (float*)alloc((size_t)NNODE * 64 * 4);
  float* resid = (float*)alloc((size_t)NNODE * 32 * 4);

  hipMemsetAsync(deg, 0, NNODE * 4, stream);
  hipMemsetAsync(cur, 0, NNODE * 4, stream);

  k_count<<<(NTOT + 255) / 256, 256, 0, stream>>>(ei, deg);
  k_scan<<<1, 256, 0, stream>>>(deg, offs, NNODE);
  k_fill<<<(NTOT + 255) / 256, 256, 0, stream>>>(ei, offs, cur, csrc, cdst);

  k_residual<<<NNODE / 8, 256, 0, stream>>>(x, lin1_w, lin1_b, resid, NNODE);

  // layer 1
  k_gemm_dual<128, 512><<<dim3(NNODE / 8, 4), 256, 0, stream>>>(x, wl1, wr1, xl, xr, NNODE);
  k_score<512, 8><<<(NTOT + 3) / 4, 256, 0, stream>>>(xl, xr, att1, csrc, cdst, ebuf);
  k_agg1<<<(NNODE + 3) / 4, 256, 0, stream>>>(xl, ebuf, csrc, offs, b1, h1);

  // layer 2
  k_gemm_dual<64, 256><<<dim3(NNODE / 8, 2), 256, 0, stream>>>(h1, wl2, wr2, xl, xr, NNODE);
  k_score<256, 4><<<(NTOT + 3) / 4, 256, 0, stream>>>(xl, xr, att2, csrc, cdst, ebuf);
  k_agg2<<<(NNODE + 3) / 4, 256, 0, stream>>>(xl, ebuf, csrc, offs, b2, resid, out);
}

// Round 3
// 722.758 us; speedup vs baseline: 1.4950x; 1.4950x over previous
//
#include <hip/hip_runtime.h>
#include <hip/hip_bf16.h>

#define NNODE 50000
#define NEDGE 400000
#define NTOT  450000   // NEDGE + NNODE self-loops
#define FDIM  128
#define HEADS 8

typedef __bf16 bf16x8 __attribute__((ext_vector_type(8)));
typedef float  f32x4  __attribute__((ext_vector_type(4)));
typedef unsigned short u16x8 __attribute__((ext_vector_type(8)));
typedef unsigned short u16x4 __attribute__((ext_vector_type(4)));
typedef __hip_bfloat16 bf16;

static __device__ __forceinline__ float lrelu(float v) {
  return v > 0.f ? v : 0.2f * v;
}
static __device__ __forceinline__ float b2f(unsigned short u) {
  union { float f; unsigned int i; } x; x.i = ((unsigned int)u) << 16; return x.f;
}

// ---------------- CSR build ----------------

__global__ __launch_bounds__(256) void k_count(const int* __restrict__ ei, int* __restrict__ deg) {
  int t = blockIdx.x * 256 + threadIdx.x;
  if (t >= NTOT) return;
  int d = (t < NEDGE) ? ei[NEDGE + t] : (t - NEDGE);
  atomicAdd(&deg[d], 1);
}

__global__ __launch_bounds__(256) void k_scan(const int* __restrict__ deg, int* __restrict__ offs, int n) {
  __shared__ int buf[256];
  __shared__ int carry;
  if (threadIdx.x == 0) carry = 0;
  __syncthreads();
  for (int base = 0; base < n; base += 256) {
    int i = base + threadIdx.x;
    int v = (i < n) ? deg[i] : 0;
    buf[threadIdx.x] = v;
    __syncthreads();
    for (int off = 1; off < 256; off <<= 1) {
      int t = (threadIdx.x >= off) ? buf[threadIdx.x - off] : 0;
      __syncthreads();
      buf[threadIdx.x] += t;
      __syncthreads();
    }
    if (i < n) offs[i + 1] = carry + buf[threadIdx.x];
    __syncthreads();
    if (threadIdx.x == 255) carry += buf[255];
    __syncthreads();
  }
  if (threadIdx.x == 0) offs[0] = 0;
}

__global__ __launch_bounds__(256) void k_fill(const int* __restrict__ ei, const int* __restrict__ offs,
                                              int* __restrict__ cur, int* __restrict__ csrc,
                                              int* __restrict__ cdst) {
  int t = blockIdx.x * 256 + threadIdx.x;
  if (t >= NTOT) return;
  int s, d;
  if (t < NEDGE) { s = ei[t]; d = ei[NEDGE + t]; }
  else { s = t - NEDGE; d = s; }
  int pos = offs[d] + atomicAdd(&cur[d], 1);
  csrc[pos] = s;
  cdst[pos] = d;
}

// ---------------- fp32 -> bf16 cast ----------------

__global__ __launch_bounds__(256) void k_cast(const float* __restrict__ in, bf16* __restrict__ o, int nvec) {
  int t = blockIdx.x * 256 + threadIdx.x;
  if (t >= nvec) return;
  float4 v = *(const float4*)(in + (size_t)t * 4);
  bf16* p = o + (size_t)t * 4;
  p[0] = __float2bfloat16(v.x);
  p[1] = __float2bfloat16(v.y);
  p[2] = __float2bfloat16(v.z);
  p[3] = __float2bfloat16(v.w);
}

// ---------------- B pre-pack into MFMA fragment order ----------------
// B = [Wl | Wr], each K x (N/2) fp32 row-major.
// Bp[((cb*KS + ks)*64 + lane)*8 + j] = bf16( B[k = ks*32 + (lane>>4)*8 + j][col = cb*16 + (lane&15)] )

template<int K, int N>
__global__ __launch_bounds__(256) void k_pack(const float* __restrict__ Wl, const float* __restrict__ Wr,
                                              bf16* __restrict__ Bp) {
  constexpr int KS = K / 32;
  int t = blockIdx.x * 256 + threadIdx.x;
  if (t >= (N / 16) * KS * 64) return;
  int lane = t & 63;
  int ks = (t >> 6) % KS;
  int cb = t / (64 * KS);
  int col = cb * 16 + (lane & 15);
  int k0 = ks * 32 + (lane >> 4) * 8;
  const float* W = (col < N / 2) ? Wl : Wr;
  int c = (col < N / 2) ? col : col - N / 2;
  bf16* o = Bp + (size_t)t * 8;
#pragma unroll
  for (int j = 0; j < 8; ++j)
    o[j] = __float2bfloat16(W[(size_t)(k0 + j) * (N / 2) + c]);
}

// ---------------- MFMA dual GEMM ----------------
// A: n x K bf16. Bp packed as above. Out: xl, xr each n x (N/2) bf16.
// Block 256 = 4 waves. Block tile: 32 rows x 256 cols. Wave: 32 x 64.

template<int K, int N>
__global__ __launch_bounds__(256) void k_mfma(const bf16* __restrict__ A,
                                              const bf16* __restrict__ Bp,
                                              bf16* __restrict__ xl, bf16* __restrict__ xr,
                                              int n) {
  constexpr int KS = K / 32;
  const int lane = threadIdx.x & 63;
  const int wave = threadIdx.x >> 6;
  const int rb = blockIdx.x * 32;
  const int cb0 = blockIdx.y * 16 + wave * 4;
  const int r16 = lane & 15, kg = lane >> 4;

  bf16x8 a[2][KS];
#pragma unroll
  for (int mf = 0; mf < 2; ++mf) {
    int row = rb + 16 * mf + r16;
    if (row >= n) row = n - 1;
    const bf16* pa = A + (size_t)row * K + kg * 8;
#pragma unroll
    for (int ks = 0; ks < KS; ++ks)
      a[mf][ks] = *(const bf16x8*)(pa + ks * 32);
  }

#pragma unroll
  for (int nf = 0; nf < 4; ++nf) {
    int cb = cb0 + nf;
    f32x4 acc0 = {0.f, 0.f, 0.f, 0.f}, acc1 = {0.f, 0.f, 0.f, 0.f};
    const bf16* pb = Bp + (size_t)cb * KS * 512 + lane * 8;
#pragma unroll
    for (int ks = 0; ks < KS; ++ks) {
      bf16x8 b = *(const bf16x8*)(pb + ks * 512);
      acc0 = __builtin_amdgcn_mfma_f32_16x16x32_bf16(a[0][ks], b, acc0, 0, 0, 0);
      acc1 = __builtin_amdgcn_mfma_f32_16x16x32_bf16(a[1][ks], b, acc1, 0, 0, 0);
    }
    int col = cb * 16 + r16;
    bf16* OUT; int c;
    if (col < N / 2) { OUT = xl; c = col; } else { OUT = xr; c = col - N / 2; }
#pragma unroll
    for (int reg = 0; reg < 4; ++reg) {
      int row0 = rb + kg * 4 + reg;
      if (row0 < n) OUT[(size_t)row0 * (N / 2) + c] = __float2bfloat16(acc0[reg]);
      int row1 = rb + 16 + kg * 4 + reg;
      if (row1 < n) OUT[(size_t)row1 * (N / 2) + c] = __float2bfloat16(acc1[reg]);
    }
  }
}

// ---------------- residual (fp32 vector; small) ----------------

__global__ __launch_bounds__(256) void k_residual(const float* __restrict__ X,
                                                  const float* __restrict__ W,
                                                  const float* __restrict__ b,
                                                  float* __restrict__ out, int n) {
  __shared__ float xs[8 * 128];
  int row0 = blockIdx.x * 8;
  for (int t = threadIdx.x; t < 8 * 128; t += 256) {
    int r = t >> 7;
    xs[t] = (row0 + r < n) ? X[(size_t)(row0 + r) * 128 + (t & 127)] : 0.f;
  }
  __syncthreads();
  int r = threadIdx.x >> 5, c = threadIdx.x & 31;
  float acc = 0.f;
  for (int k = 0; k < 128; ++k) acc += xs[r * 128 + k] * W[k * 32 + c];
  if (row0 + r < n) out[(size_t)(row0 + r) * 32 + c] = acc + b[c];
}

// ---------------- edge scores (bf16 gathers) ----------------

template<int D, int VEC>
__global__ __launch_bounds__(256) void k_score(const bf16* __restrict__ xl,
                                               const bf16* __restrict__ xr,
                                               const float* __restrict__ att,
                                               const int* __restrict__ csrc,
                                               const int* __restrict__ cdst,
                                               float* __restrict__ ebuf) {
  int slot = blockIdx.x * 4 + (threadIdx.x >> 6);
  int lane = threadIdx.x & 63;
  if (slot >= NTOT) return;
  int s = csrc[slot], d = cdst[slot];
  const unsigned short* pl = (const unsigned short*)(xl + (size_t)s * D) + lane * VEC;
  const unsigned short* pr = (const unsigned short*)(xr + (size_t)d * D) + lane * VEC;
  const float* pa = att + lane * VEC;
  float acc = 0.f;
  if constexpr (VEC == 8) {
    u16x8 a = *(const u16x8*)pl;
    u16x8 b = *(const u16x8*)pr;
#pragma unroll
    for (int v = 0; v < 8; ++v)
      acc += lrelu(b2f(a[v]) + b2f(b[v])) * pa[v];
  } else {
    u16x4 a = *(const u16x4*)pl;
    u16x4 b = *(const u16x4*)pr;
#pragma unroll
    for (int v = 0; v < 4; ++v)
      acc += lrelu(b2f(a[v]) + b2f(b[v])) * pa[v];
  }
  acc += __shfl_xor(acc, 1);
  acc += __shfl_xor(acc, 2);
  acc += __shfl_xor(acc, 4);
  if ((lane & 7) == 0) ebuf[(size_t)slot * 8 + (lane >> 3)] = acc;
}

// ---------------- per-node softmax + aggregate ----------------

// Layer 1: D=512 (8 heads x 64). lane = channel. Output bf16 (feeds GEMM2) with ReLU.
__global__ __launch_bounds__(256) void k_agg1(const bf16* __restrict__ xl,
                                              const float* __restrict__ ebuf,
                                              const int* __restrict__ csrc,
                                              const int* __restrict__ offs,
                                              const float* __restrict__ bias,
                                              bf16* __restrict__ out) {
  int node = blockIdx.x * 4 + (threadIdx.x >> 6);
  int lane = threadIdx.x & 63;
  if (node >= NNODE) return;
  int beg = offs[node], end = offs[node + 1];
  float m[8];
#pragma unroll
  for (int h = 0; h < 8; ++h) m[h] = -1e30f;
  for (int i = beg; i < end; ++i) {
#pragma unroll
    for (int h = 0; h < 8; ++h) m[h] = fmaxf(m[h], ebuf[(size_t)i * 8 + h]);
  }
  float sden[8] = {0,0,0,0,0,0,0,0}, acc[8] = {0,0,0,0,0,0,0,0};
  for (int i = beg; i < end; ++i) {
    int s = csrc[i];
    const unsigned short* p = (const unsigned short*)(xl + (size_t)s * 512);
#pragma unroll
    for (int h = 0; h < 8; ++h) {
      float w = __expf(ebuf[(size_t)i * 8 + h] - m[h]);
      sden[h] += w;
      acc[h] += w * b2f(p[h * 64 + lane]);
    }
  }
  float o = 0.f;
#pragma unroll
  for (int h = 0; h < 8; ++h) o += acc[h] / sden[h];
  o = o * 0.125f + bias[lane];
  o = fmaxf(o, 0.f);
  out[(size_t)node * 64 + lane] = __float2bfloat16(o);
}

// Layer 2: D=256 (8 heads x 32). lanes 0-31: heads 0-3, lanes 32-63: heads 4-7.
__global__ __launch_bounds__(256) void k_agg2(const bf16* __restrict__ xl,
                                              const float* __restrict__ ebuf,
                                              const int* __restrict__ csrc,
                                              const int* __restrict__ offs,
                                              const float* __restrict__ bias,
                                              const float* __restrict__ resid,
                                              float* __restrict__ out) {
  int node = blockIdx.x * 4 + (threadIdx.x >> 6);
  int lane = threadIdx.x & 63;
  if (node >= NNODE) return;
  int half = lane >> 5, c = lane & 31;
  int beg = offs[node], end = offs[node + 1];
  float m[4];
#pragma unroll
  for (int j = 0; j < 4; ++j) m[j] = -1e30f;
  for (int i = beg; i < end; ++i) {
#pragma unroll
    for (int j = 0; j < 4; ++j) m[j] = fmaxf(m[j], ebuf[(size_t)i * 8 + half * 4 + j]);
  }
  float sden[4] = {0,0,0,0}, acc[4] = {0,0,0,0};
  for (int i = beg; i < end; ++i) {
    int s = csrc[i];
    const unsigned short* p = (const unsigned short*)(xl + (size_t)s * 256);
#pragma unroll
    for (int j = 0; j < 4; ++j) {
      float w = __expf(ebuf[(size_t)i * 8 + half * 4 + j] - m[j]);
      sden[j] += w;
      acc[j] += w * b2f(p[(half * 4 + j) * 32 + c]);
    }
  }
  float o = 0.f;
#pragma unroll
  for (int j = 0; j < 4; ++j) o += acc[j] / sden[j];
  o += __shfl_xor(o, 32);
  o = o * 0.125f + bias[c] + resid[(size_t)node * 32 + c];
  if (half == 0) out[(size_t)node * 32 + c] = o;
}

// ---------------- launch ----------------

extern "C" void kernel_launch(void* const* d_in, const int* in_sizes, int n_in,
                              void* d_out, int out_size, void* d_ws, size_t ws_size,
                              hipStream_t stream) {
  const float* x      = (const float*)d_in[0];
  const int*   ei     = (const int*)d_in[1];
  const float* lin1_w = (const float*)d_in[3];
  const float* lin1_b = (const float*)d_in[4];
  const float* wl1    = (const float*)d_in[5];
  const float* wr1    = (const float*)d_in[6];
  const float* att1   = (const float*)d_in[7];
  const float* b1     = (const float*)d_in[8];
  const float* wl2    = (const float*)d_in[9];
  const float* wr2    = (const float*)d_in[10];
  const float* att2   = (const float*)d_in[11];
  const float* b2     = (const float*)d_in[12];
  float* out = (float*)d_out;

  char* p = (char*)d_ws;
  auto alloc = [&](size_t bytes) {
    char* r = p;
    p += (bytes + 255) & ~size_t(255);
    return r;
  };
  int*   offs  = (int*)alloc((NNODE + 1) * 4);
  int*   deg   = (int*)alloc(NNODE * 4);
  int*   cur   = (int*)alloc(NNODE * 4);
  int*   csrc  = (int*)alloc((size_t)NTOT * 4);
  int*   cdst  = (int*)alloc((size_t)NTOT * 4);
  float* ebuf  = (float*)alloc((size_t)NTOT * 8 * 4);
  bf16*  xb    = (bf16*)alloc((size_t)NNODE * 128 * 2);   // x cast to bf16
  bf16*  xl    = (bf16*)alloc((size_t)NNODE * 512 * 2);   // layer1 xl / reused layer2 xl
  bf16*  xr    = (bf16*)alloc((size_t)NNODE * 512 * 2);
  bf16*  h1    = (bf16*)alloc((size_t)NNODE * 64 * 2);
  bf16*  Bp1   = (bf16*)alloc((size_t)128 * 1024 * 2);
  bf16*  Bp2   = (bf16*)alloc((size_t)64 * 512 * 2);
  float* resid = (float*)alloc((size_t)NNODE * 32 * 4);

  (void)hipMemsetAsync(deg, 0, NNODE * 4, stream);
  (void)hipMemsetAsync(cur, 0, NNODE * 4, stream);

  // prep
  k_count<<<(NTOT + 255) / 256, 256, 0, stream>>>(ei, deg);
  k_scan<<<1, 256, 0, stream>>>(deg, offs, NNODE);
  k_fill<<<(NTOT + 255) / 256, 256, 0, stream>>>(ei, offs, cur, csrc, cdst);
  k_cast<<<(NNODE * 128 / 4 + 255) / 256, 256, 0, stream>>>(x, xb, NNODE * 128 / 4);
  k_pack<128, 1024><<<64, 256, 0, stream>>>(wl1, wr1, Bp1);
  k_pack<64, 512><<<16, 256, 0, stream>>>(wl2, wr2, Bp2);
  k_residual<<<NNODE / 8, 256, 0, stream>>>(x, lin1_w, lin1_b, resid, NNODE);

  // layer 1
  k_mfma<128, 1024><<<dim3((NNODE + 31) / 32, 4), 256, 0, stream>>>(xb, Bp1, xl, xr, NNODE);
  k_score<512, 8><<<(NTOT + 3) / 4, 256, 0, stream>>>(xl, xr, att1, csrc, cdst, ebuf);
  k_agg1<<<(NNODE + 3) / 4, 256, 0, stream>>>(xl, ebuf, csrc, offs, b1, h1);

  // layer 2
  k_mfma<64, 512><<<dim3((NNODE + 31) / 32, 2), 256, 0, stream>>>(h1, Bp2, xl, xr, NNODE);
  k_score<256, 4><<<(NTOT + 3) / 4, 256, 0, stream>>>(xl, xr, att2, csrc, cdst, ebuf);
  k_agg2<<<(NNODE + 3) / 4, 256, 0, stream>>>(xl, ebuf, csrc, offs, b2, resid, out);
}

// Round 4
// 519.512 us; speedup vs baseline: 2.0799x; 1.3912x over previous
//
#include <hip/hip_runtime.h>
#include <hip/hip_bf16.h>

#define NNODE 50000
#define NEDGE 400000
#define NTOT  450000   // NEDGE + NNODE self-loops
#define FDIM  128
#define HEADS 8
#define SCANB ((NNODE + 255) / 256)   // 196 blocks

typedef __bf16 bf16x8 __attribute__((ext_vector_type(8)));
typedef float  f32x4  __attribute__((ext_vector_type(4)));
typedef unsigned short u16x8 __attribute__((ext_vector_type(8)));
typedef unsigned short u16x4 __attribute__((ext_vector_type(4)));
typedef __hip_bfloat16 bf16;

static __device__ __forceinline__ float lrelu(float v) {
  return v > 0.f ? v : 0.2f * v;
}
static __device__ __forceinline__ float b2f(unsigned short u) {
  union { float f; unsigned int i; } x; x.i = ((unsigned int)u) << 16; return x.f;
}

// ---------------- CSR build ----------------

__global__ __launch_bounds__(256) void k_count(const int* __restrict__ ei, int* __restrict__ deg) {
  int t = blockIdx.x * 256 + threadIdx.x;
  if (t >= NTOT) return;
  int d = (t < NEDGE) ? ei[NEDGE + t] : (t - NEDGE);
  atomicAdd(&deg[d], 1);
}

// hierarchical scan: per-block inclusive scan + block sums
__global__ __launch_bounds__(256) void k_scan1(const int* __restrict__ deg, int* __restrict__ offs,
                                               int* __restrict__ bsum) {
  __shared__ int buf[256];
  int i = blockIdx.x * 256 + threadIdx.x;
  int v = (i < NNODE) ? deg[i] : 0;
  buf[threadIdx.x] = v;
  __syncthreads();
  for (int off = 1; off < 256; off <<= 1) {
    int t = (threadIdx.x >= off) ? buf[threadIdx.x - off] : 0;
    __syncthreads();
    buf[threadIdx.x] += t;
    __syncthreads();
  }
  if (i < NNODE) offs[i + 1] = buf[threadIdx.x];
  if (threadIdx.x == 255) bsum[blockIdx.x] = buf[255];
  if (i == 0) offs[0] = 0;
}

// exclusive scan of block sums (nb <= 256, one block)
__global__ __launch_bounds__(256) void k_scan2(int* __restrict__ bsum, int nb) {
  __shared__ int buf[256];
  int v = (threadIdx.x < nb) ? bsum[threadIdx.x] : 0;
  buf[threadIdx.x] = v;
  __syncthreads();
  for (int off = 1; off < 256; off <<= 1) {
    int t = (threadIdx.x >= off) ? buf[threadIdx.x - off] : 0;
    __syncthreads();
    buf[threadIdx.x] += t;
    __syncthreads();
  }
  if (threadIdx.x < nb) bsum[threadIdx.x] = buf[threadIdx.x] - v;
}

// uniform add
__global__ __launch_bounds__(256) void k_scan3(int* __restrict__ offs, const int* __restrict__ bsum) {
  int i = blockIdx.x * 256 + threadIdx.x;
  if (i < NNODE) offs[i + 1] += bsum[blockIdx.x];
}

__global__ __launch_bounds__(256) void k_fill(const int* __restrict__ ei, const int* __restrict__ offs,
                                              int* __restrict__ cur, int* __restrict__ csrc,
                                              int* __restrict__ cdst) {
  int t = blockIdx.x * 256 + threadIdx.x;
  if (t >= NTOT) return;
  int s, d;
  if (t < NEDGE) { s = ei[t]; d = ei[NEDGE + t]; }
  else { s = t - NEDGE; d = s; }
  int pos = offs[d] + atomicAdd(&cur[d], 1);
  csrc[pos] = s;
  cdst[pos] = d;
}

// ---------------- fp32 -> bf16 cast ----------------

__global__ __launch_bounds__(256) void k_cast(const float* __restrict__ in, bf16* __restrict__ o, int nvec) {
  int t = blockIdx.x * 256 + threadIdx.x;
  if (t >= nvec) return;
  float4 v = *(const float4*)(in + (size_t)t * 4);
  bf16* p = o + (size_t)t * 4;
  p[0] = __float2bfloat16(v.x);
  p[1] = __float2bfloat16(v.y);
  p[2] = __float2bfloat16(v.z);
  p[3] = __float2bfloat16(v.w);
}

// ---------------- B pre-pack into MFMA fragment order ----------------
// B = [Wl | Wr], each K x (N/2) fp32 row-major.
// Bp[((cb*KS + ks)*64 + lane)*8 + j] = bf16( B[k = ks*32 + (lane>>4)*8 + j][col = cb*16 + (lane&15)] )

template<int K, int N>
__global__ __launch_bounds__(256) void k_pack(const float* __restrict__ Wl, const float* __restrict__ Wr,
                                              bf16* __restrict__ Bp) {
  constexpr int KS = K / 32;
  int t = blockIdx.x * 256 + threadIdx.x;
  if (t >= (N / 16) * KS * 64) return;
  int lane = t & 63;
  int ks = (t >> 6) % KS;
  int cb = t / (64 * KS);
  int col = cb * 16 + (lane & 15);
  int k0 = ks * 32 + (lane >> 4) * 8;
  const float* W = (col < N / 2) ? Wl : Wr;
  int c = (col < N / 2) ? col : col - N / 2;
  bf16* o = Bp + (size_t)t * 8;
#pragma unroll
  for (int j = 0; j < 8; ++j)
    o[j] = __float2bfloat16(W[(size_t)(k0 + j) * (N / 2) + c]);
}

// ---------------- MFMA dual GEMM ----------------

template<int K, int N>
__global__ __launch_bounds__(256) void k_mfma(const bf16* __restrict__ A,
                                              const bf16* __restrict__ Bp,
                                              bf16* __restrict__ xl, bf16* __restrict__ xr,
                                              int n) {
  constexpr int KS = K / 32;
  const int lane = threadIdx.x & 63;
  const int wave = threadIdx.x >> 6;
  const int rb = blockIdx.x * 32;
  const int cb0 = blockIdx.y * 16 + wave * 4;
  const int r16 = lane & 15, kg = lane >> 4;

  bf16x8 a[2][KS];
#pragma unroll
  for (int mf = 0; mf < 2; ++mf) {
    int row = rb + 16 * mf + r16;
    if (row >= n) row = n - 1;
    const bf16* pa = A + (size_t)row * K + kg * 8;
#pragma unroll
    for (int ks = 0; ks < KS; ++ks)
      a[mf][ks] = *(const bf16x8*)(pa + ks * 32);
  }

#pragma unroll
  for (int nf = 0; nf < 4; ++nf) {
    int cb = cb0 + nf;
    f32x4 acc0 = {0.f, 0.f, 0.f, 0.f}, acc1 = {0.f, 0.f, 0.f, 0.f};
    const bf16* pb = Bp + (size_t)cb * KS * 512 + lane * 8;
#pragma unroll
    for (int ks = 0; ks < KS; ++ks) {
      bf16x8 b = *(const bf16x8*)(pb + ks * 512);
      acc0 = __builtin_amdgcn_mfma_f32_16x16x32_bf16(a[0][ks], b, acc0, 0, 0, 0);
      acc1 = __builtin_amdgcn_mfma_f32_16x16x32_bf16(a[1][ks], b, acc1, 0, 0, 0);
    }
    int col = cb * 16 + r16;
    bf16* OUT; int c;
    if (col < N / 2) { OUT = xl; c = col; } else { OUT = xr; c = col - N / 2; }
#pragma unroll
    for (int reg = 0; reg < 4; ++reg) {
      int row0 = rb + kg * 4 + reg;
      if (row0 < n) OUT[(size_t)row0 * (N / 2) + c] = __float2bfloat16(acc0[reg]);
      int row1 = rb + 16 + kg * 4 + reg;
      if (row1 < n) OUT[(size_t)row1 * (N / 2) + c] = __float2bfloat16(acc1[reg]);
    }
  }
}

// ---------------- residual (fp32 vector; small) ----------------

__global__ __launch_bounds__(256) void k_residual(const float* __restrict__ X,
                                                  const float* __restrict__ W,
                                                  const float* __restrict__ b,
                                                  float* __restrict__ out, int n) {
  __shared__ float xs[8 * 128];
  int row0 = blockIdx.x * 8;
  for (int t = threadIdx.x; t < 8 * 128; t += 256) {
    int r = t >> 7;
    xs[t] = (row0 + r < n) ? X[(size_t)(row0 + r) * 128 + (t & 127)] : 0.f;
  }
  __syncthreads();
  int r = threadIdx.x >> 5, c = threadIdx.x & 31;
  float acc = 0.f;
  for (int k = 0; k < 128; ++k) acc += xs[r * 128 + k] * W[k * 32 + c];
  if (row0 + r < n) out[(size_t)(row0 + r) * 32 + c] = acc + b[c];
}

// ---------------- edge scores (bf16 gathers) ----------------

template<int D, int VEC>
__global__ __launch_bounds__(256) void k_score(const bf16* __restrict__ xl,
                                               const bf16* __restrict__ xr,
                                               const float* __restrict__ att,
                                               const int* __restrict__ csrc,
                                               const int* __restrict__ cdst,
                                               float* __restrict__ ebuf) {
  int slot = blockIdx.x * 4 + (threadIdx.x >> 6);
  int lane = threadIdx.x & 63;
  if (slot >= NTOT) return;
  int s = csrc[slot], d = cdst[slot];
  const unsigned short* pl = (const unsigned short*)(xl + (size_t)s * D) + lane * VEC;
  const unsigned short* pr = (const unsigned short*)(xr + (size_t)d * D) + lane * VEC;
  const float* pa = att + lane * VEC;
  float acc = 0.f;
  if constexpr (VEC == 8) {
    u16x8 a = *(const u16x8*)pl;
    u16x8 b = *(const u16x8*)pr;
#pragma unroll
    for (int v = 0; v < 8; ++v)
      acc += lrelu(b2f(a[v]) + b2f(b[v])) * pa[v];
  } else {
    u16x4 a = *(const u16x4*)pl;
    u16x4 b = *(const u16x4*)pr;
#pragma unroll
    for (int v = 0; v < 4; ++v)
      acc += lrelu(b2f(a[v]) + b2f(b[v])) * pa[v];
  }
  acc += __shfl_xor(acc, 1);
  acc += __shfl_xor(acc, 2);
  acc += __shfl_xor(acc, 4);
  if ((lane & 7) == 0) ebuf[(size_t)slot * 8 + (lane >> 3)] = acc;
}

// ---------------- per-node softmax + aggregate ----------------

__global__ __launch_bounds__(256) void k_agg1(const bf16* __restrict__ xl,
                                              const float* __restrict__ ebuf,
                                              const int* __restrict__ csrc,
                                              const int* __restrict__ offs,
                                              const float* __restrict__ bias,
                                              bf16* __restrict__ out) {
  int node = blockIdx.x * 4 + (threadIdx.x >> 6);
  int lane = threadIdx.x & 63;
  if (node >= NNODE) return;
  int beg = offs[node], end = offs[node + 1];
  float m[8];
#pragma unroll
  for (int h = 0; h < 8; ++h) m[h] = -1e30f;
  for (int i = beg; i < end; ++i) {
#pragma unroll
    for (int h = 0; h < 8; ++h) m[h] = fmaxf(m[h], ebuf[(size_t)i * 8 + h]);
  }
  float sden[8] = {0,0,0,0,0,0,0,0}, acc[8] = {0,0,0,0,0,0,0,0};
  for (int i = beg; i < end; ++i) {
    int s = csrc[i];
    const unsigned short* p = (const unsigned short*)(xl + (size_t)s * 512);
#pragma unroll
    for (int h = 0; h < 8; ++h) {
      float w = __expf(ebuf[(size_t)i * 8 + h] - m[h]);
      sden[h] += w;
      acc[h] += w * b2f(p[h * 64 + lane]);
    }
  }
  float o = 0.f;
#pragma unroll
  for (int h = 0; h < 8; ++h) o += acc[h] / sden[h];
  o = o * 0.125f + bias[lane];
  o = fmaxf(o, 0.f);
  out[(size_t)node * 64 + lane] = __float2bfloat16(o);
}

__global__ __launch_bounds__(256) void k_agg2(const bf16* __restrict__ xl,
                                              const float* __restrict__ ebuf,
                                              const int* __restrict__ csrc,
                                              const int* __restrict__ offs,
                                              const float* __restrict__ bias,
                                              const float* __restrict__ resid,
                                              float* __restrict__ out) {
  int node = blockIdx.x * 4 + (threadIdx.x >> 6);
  int lane = threadIdx.x & 63;
  if (node >= NNODE) return;
  int half = lane >> 5, c = lane & 31;
  int beg = offs[node], end = offs[node + 1];
  float m[4];
#pragma unroll
  for (int j = 0; j < 4; ++j) m[j] = -1e30f;
  for (int i = beg; i < end; ++i) {
#pragma unroll
    for (int j = 0; j < 4; ++j) m[j] = fmaxf(m[j], ebuf[(size_t)i * 8 + half * 4 + j]);
  }
  float sden[4] = {0,0,0,0}, acc[4] = {0,0,0,0};
  for (int i = beg; i < end; ++i) {
    int s = csrc[i];
    const unsigned short* p = (const unsigned short*)(xl + (size_t)s * 256);
#pragma unroll
    for (int j = 0; j < 4; ++j) {
      float w = __expf(ebuf[(size_t)i * 8 + half * 4 + j] - m[j]);
      sden[j] += w;
      acc[j] += w * b2f(p[(half * 4 + j) * 32 + c]);
    }
  }
  float o = 0.f;
#pragma unroll
  for (int j = 0; j < 4; ++j) o += acc[j] / sden[j];
  o += __shfl_xor(o, 32);
  o = o * 0.125f + bias[c] + resid[(size_t)node * 32 + c];
  if (half == 0) out[(size_t)node * 32 + c] = o;
}

// ---------------- launch ----------------

extern "C" void kernel_launch(void* const* d_in, const int* in_sizes, int n_in,
                              void* d_out, int out_size, void* d_ws, size_t ws_size,
                              hipStream_t stream) {
  const float* x      = (const float*)d_in[0];
  const int*   ei     = (const int*)d_in[1];
  const float* lin1_w = (const float*)d_in[3];
  const float* lin1_b = (const float*)d_in[4];
  const float* wl1    = (const float*)d_in[5];
  const float* wr1    = (const float*)d_in[6];
  const float* att1   = (const float*)d_in[7];
  const float* b1     = (const float*)d_in[8];
  const float* wl2    = (const float*)d_in[9];
  const float* wr2    = (const float*)d_in[10];
  const float* att2   = (const float*)d_in[11];
  const float* b2     = (const float*)d_in[12];
  float* out = (float*)d_out;

  char* p = (char*)d_ws;
  auto alloc = [&](size_t bytes) {
    char* r = p;
    p += (bytes + 255) & ~size_t(255);
    return r;
  };
  int*   offs  = (int*)alloc((NNODE + 1) * 4);
  int*   deg   = (int*)alloc(NNODE * 4);
  int*   cur   = (int*)alloc(NNODE * 4);
  int*   bsum  = (int*)alloc(SCANB * 4);
  int*   csrc  = (int*)alloc((size_t)NTOT * 4);
  int*   cdst  = (int*)alloc((size_t)NTOT * 4);
  float* ebuf  = (float*)alloc((size_t)NTOT * 8 * 4);
  bf16*  xb    = (bf16*)alloc((size_t)NNODE * 128 * 2);
  bf16*  xl    = (bf16*)alloc((size_t)NNODE * 512 * 2);
  bf16*  xr    = (bf16*)alloc((size_t)NNODE * 512 * 2);
  bf16*  h1    = (bf16*)alloc((size_t)NNODE * 64 * 2);
  bf16*  Bp1   = (bf16*)alloc((size_t)128 * 1024 * 2);
  bf16*  Bp2   = (bf16*)alloc((size_t)64 * 512 * 2);
  float* resid = (float*)alloc((size_t)NNODE * 32 * 4);

  (void)hipMemsetAsync(deg, 0, NNODE * 4, stream);
  (void)hipMemsetAsync(cur, 0, NNODE * 4, stream);

  // prep
  k_count<<<(NTOT + 255) / 256, 256, 0, stream>>>(ei, deg);
  k_scan1<<<SCANB, 256, 0, stream>>>(deg, offs, bsum);
  k_scan2<<<1, 256, 0, stream>>>(bsum, SCANB);
  k_scan3<<<SCANB, 256, 0, stream>>>(offs, bsum);
  k_fill<<<(NTOT + 255) / 256, 256, 0, stream>>>(ei, offs, cur, csrc, cdst);
  k_cast<<<(NNODE * 128 / 4 + 255) / 256, 256, 0, stream>>>(x, xb, NNODE * 128 / 4);
  k_pack<128, 1024><<<64, 256, 0, stream>>>(wl1, wr1, Bp1);
  k_pack<64, 512><<<16, 256, 0, stream>>>(wl2, wr2, Bp2);
  k_residual<<<NNODE / 8, 256, 0, stream>>>(x, lin1_w, lin1_b, resid, NNODE);

  // layer 1
  k_mfma<128, 1024><<<dim3((NNODE + 31) / 32, 4), 256, 0, stream>>>(xb, Bp1, xl, xr, NNODE);
  k_score<512, 8><<<(NTOT + 3) / 4, 256, 0, stream>>>(xl, xr, att1, csrc, cdst, ebuf);
  k_agg1<<<(NNODE + 3) / 4, 256, 0, stream>>>(xl, ebuf, csrc, offs, b1, h1);

  // layer 2
  k_mfma<64, 512><<<dim3((NNODE + 31) / 32, 2), 256, 0, stream>>>(h1, Bp2, xl, xr, NNODE);
  k_score<256, 4><<<(NTOT + 3) / 4, 256, 0, stream>>>(xl, xr, att2, csrc, cdst, ebuf);
  k_agg2<<<(NNODE + 3) / 4, 256, 0, stream>>>(xl, ebuf, csrc, offs, b2, resid, out);
}

// Round 5
// 327.063 us; speedup vs baseline: 3.3038x; 1.5884x over previous
//
#include <hip/hip_runtime.h>
#include <hip/hip_bf16.h>

#define NNODE 50000
#define NEDGE 400000
#define NTOT  450000   // NEDGE + NNODE self-loops
#define FDIM  128
#define HEADS 8
#define SCANB ((NNODE + 255) / 256)   // 196 blocks

typedef __bf16 bf16x8 __attribute__((ext_vector_type(8)));
typedef float  f32x4  __attribute__((ext_vector_type(4)));
typedef unsigned short u16x8 __attribute__((ext_vector_type(8)));
typedef unsigned short u16x4 __attribute__((ext_vector_type(4)));
typedef __hip_bfloat16 bf16;

static __device__ __forceinline__ float lrelu(float v) {
  return v > 0.f ? v : 0.2f * v;
}
static __device__ __forceinline__ float b2f(unsigned short u) {
  union { float f; unsigned int i; } x; x.i = ((unsigned int)u) << 16; return x.f;
}

// ---------------- CSR build ----------------

__global__ __launch_bounds__(256) void k_count(const int* __restrict__ ei, int* __restrict__ deg) {
  int t = blockIdx.x * 256 + threadIdx.x;
  if (t >= NTOT) return;
  int d = (t < NEDGE) ? ei[NEDGE + t] : (t - NEDGE);
  atomicAdd(&deg[d], 1);
}

__global__ __launch_bounds__(256) void k_scan1(const int* __restrict__ deg, int* __restrict__ offs,
                                               int* __restrict__ bsum) {
  __shared__ int buf[256];
  int i = blockIdx.x * 256 + threadIdx.x;
  int v = (i < NNODE) ? deg[i] : 0;
  buf[threadIdx.x] = v;
  __syncthreads();
  for (int off = 1; off < 256; off <<= 1) {
    int t = (threadIdx.x >= off) ? buf[threadIdx.x - off] : 0;
    __syncthreads();
    buf[threadIdx.x] += t;
    __syncthreads();
  }
  if (i < NNODE) offs[i + 1] = buf[threadIdx.x];
  if (threadIdx.x == 255) bsum[blockIdx.x] = buf[255];
  if (i == 0) offs[0] = 0;
}

__global__ __launch_bounds__(256) void k_scan2(int* __restrict__ bsum, int nb) {
  __shared__ int buf[256];
  int v = (threadIdx.x < nb) ? bsum[threadIdx.x] : 0;
  buf[threadIdx.x] = v;
  __syncthreads();
  for (int off = 1; off < 256; off <<= 1) {
    int t = (threadIdx.x >= off) ? buf[threadIdx.x - off] : 0;
    __syncthreads();
    buf[threadIdx.x] += t;
    __syncthreads();
  }
  if (threadIdx.x < nb) bsum[threadIdx.x] = buf[threadIdx.x] - v;
}

__global__ __launch_bounds__(256) void k_scan3(int* __restrict__ offs, const int* __restrict__ bsum) {
  int i = blockIdx.x * 256 + threadIdx.x;
  if (i < NNODE) offs[i + 1] += bsum[blockIdx.x];
}

__global__ __launch_bounds__(256) void k_fill(const int* __restrict__ ei, const int* __restrict__ offs,
                                              int* __restrict__ cur, int* __restrict__ csrc) {
  int t = blockIdx.x * 256 + threadIdx.x;
  if (t >= NTOT) return;
  int s, d;
  if (t < NEDGE) { s = ei[t]; d = ei[NEDGE + t]; }
  else { s = t - NEDGE; d = s; }
  int pos = offs[d] + atomicAdd(&cur[d], 1);
  csrc[pos] = s;
}

// ---------------- fp32 -> bf16 cast ----------------

__global__ __launch_bounds__(256) void k_cast(const float* __restrict__ in, bf16* __restrict__ o, int nvec) {
  int t = blockIdx.x * 256 + threadIdx.x;
  if (t >= nvec) return;
  float4 v = *(const float4*)(in + (size_t)t * 4);
  bf16* p = o + (size_t)t * 4;
  p[0] = __float2bfloat16(v.x);
  p[1] = __float2bfloat16(v.y);
  p[2] = __float2bfloat16(v.z);
  p[3] = __float2bfloat16(v.w);
}

// ---------------- B pre-pack into MFMA fragment order ----------------

template<int K, int N>
__global__ __launch_bounds__(256) void k_pack(const float* __restrict__ Wl, const float* __restrict__ Wr,
                                              bf16* __restrict__ Bp) {
  constexpr int KS = K / 32;
  int t = blockIdx.x * 256 + threadIdx.x;
  if (t >= (N / 16) * KS * 64) return;
  int lane = t & 63;
  int ks = (t >> 6) % KS;
  int cb = t / (64 * KS);
  int col = cb * 16 + (lane & 15);
  int k0 = ks * 32 + (lane >> 4) * 8;
  const float* W = (col < N / 2) ? Wl : Wr;
  int c = (col < N / 2) ? col : col - N / 2;
  bf16* o = Bp + (size_t)t * 8;
#pragma unroll
  for (int j = 0; j < 8; ++j)
    o[j] = __float2bfloat16(W[(size_t)(k0 + j) * (N / 2) + c]);
}

// ---------------- MFMA dual GEMM ----------------

template<int K, int N>
__global__ __launch_bounds__(256) void k_mfma(const bf16* __restrict__ A,
                                              const bf16* __restrict__ Bp,
                                              bf16* __restrict__ xl, bf16* __restrict__ xr,
                                              int n) {
  constexpr int KS = K / 32;
  const int lane = threadIdx.x & 63;
  const int wave = threadIdx.x >> 6;
  const int rb = blockIdx.x * 32;
  const int cb0 = blockIdx.y * 16 + wave * 4;
  const int r16 = lane & 15, kg = lane >> 4;

  bf16x8 a[2][KS];
#pragma unroll
  for (int mf = 0; mf < 2; ++mf) {
    int row = rb + 16 * mf + r16;
    if (row >= n) row = n - 1;
    const bf16* pa = A + (size_t)row * K + kg * 8;
#pragma unroll
    for (int ks = 0; ks < KS; ++ks)
      a[mf][ks] = *(const bf16x8*)(pa + ks * 32);
  }

#pragma unroll
  for (int nf = 0; nf < 4; ++nf) {
    int cb = cb0 + nf;
    f32x4 acc0 = {0.f, 0.f, 0.f, 0.f}, acc1 = {0.f, 0.f, 0.f, 0.f};
    const bf16* pb = Bp + (size_t)cb * KS * 512 + lane * 8;
#pragma unroll
    for (int ks = 0; ks < KS; ++ks) {
      bf16x8 b = *(const bf16x8*)(pb + ks * 512);
      acc0 = __builtin_amdgcn_mfma_f32_16x16x32_bf16(a[0][ks], b, acc0, 0, 0, 0);
      acc1 = __builtin_amdgcn_mfma_f32_16x16x32_bf16(a[1][ks], b, acc1, 0, 0, 0);
    }
    int col = cb * 16 + r16;
    bf16* OUT; int c;
    if (col < N / 2) { OUT = xl; c = col; } else { OUT = xr; c = col - N / 2; }
#pragma unroll
    for (int reg = 0; reg < 4; ++reg) {
      int row0 = rb + kg * 4 + reg;
      if (row0 < n) OUT[(size_t)row0 * (N / 2) + c] = __float2bfloat16(acc0[reg]);
      int row1 = rb + 16 + kg * 4 + reg;
      if (row1 < n) OUT[(size_t)row1 * (N / 2) + c] = __float2bfloat16(acc1[reg]);
    }
  }
}

// ---------------- residual (fp32 vector; small) ----------------

__global__ __launch_bounds__(256) void k_residual(const float* __restrict__ X,
                                                  const float* __restrict__ W,
                                                  const float* __restrict__ b,
                                                  float* __restrict__ out, int n) {
  __shared__ float xs[8 * 128];
  int row0 = blockIdx.x * 8;
  for (int t = threadIdx.x; t < 8 * 128; t += 256) {
    int r = t >> 7;
    xs[t] = (row0 + r < n) ? X[(size_t)(row0 + r) * 128 + (t & 127)] : 0.f;
  }
  __syncthreads();
  int r = threadIdx.x >> 5, c = threadIdx.x & 31;
  float acc = 0.f;
  for (int k = 0; k < 128; ++k) acc += xs[r * 128 + k] * W[k * 32 + c];
  if (row0 + r < n) out[(size_t)(row0 + r) * 32 + c] = acc + b[c];
}

// ---------------- fused GATv2 layer: score + online softmax + aggregate ----------------
// One wave per dst node. Lane l: head h = l>>3, sub s = l&7, channels c = s*VEC + [0..VEC).
// D = 8 heads * CH, CH = 8*VEC. att index for (h,c) = l*VEC + j (contiguous per lane).
// L1: out1 = bf16 h1[n x CH] with ReLU(mean/8 + bias). !L1: out2 = fp32[n x CH] + bias + resid.

template<int D, int VEC, bool L1>
__global__ __launch_bounds__(256) void k_gat(const bf16* __restrict__ xl,
                                             const bf16* __restrict__ xr,
                                             const float* __restrict__ att,
                                             const int* __restrict__ csrc,
                                             const int* __restrict__ offs,
                                             const float* __restrict__ bias,
                                             const float* __restrict__ resid,
                                             bf16* __restrict__ out1,
                                             float* __restrict__ out2) {
  constexpr int CH = D / 8;
  int node = blockIdx.x * 4 + (threadIdx.x >> 6);
  int lane = threadIdx.x & 63;
  if (node >= NNODE) return;
  int beg = offs[node], end = offs[node + 1];

  // per-lane constants: att and xr[node] slices
  float attv[VEC], xrv[VEC];
  {
    const float* pa = att + lane * VEC;
    const unsigned short* pr = (const unsigned short*)(xr + (size_t)node * D) + lane * VEC;
#pragma unroll
    for (int j = 0; j < VEC; ++j) { attv[j] = pa[j]; xrv[j] = b2f(pr[j]); }
  }

  float m = -1e30f, den = 0.f;
  float acc[VEC];
#pragma unroll
  for (int j = 0; j < VEC; ++j) acc[j] = 0.f;

  typedef unsigned short uvec __attribute__((ext_vector_type(VEC)));
  const unsigned short* xlb = (const unsigned short*)xl;

  uvec a_cur = *(const uvec*)(xlb + (size_t)csrc[beg] * D + lane * VEC);
  for (int i = beg; i < end; ++i) {
    uvec a_next = a_cur;
    if (i + 1 < end)
      a_next = *(const uvec*)(xlb + (size_t)csrc[i + 1] * D + lane * VEC);
    // convert current row slice
    float av[VEC];
#pragma unroll
    for (int j = 0; j < VEC; ++j) av[j] = b2f(a_cur[j]);
    // score partial + per-head reduce (8 lanes per head)
    float sc = 0.f;
#pragma unroll
    for (int j = 0; j < VEC; ++j) sc += lrelu(av[j] + xrv[j]) * attv[j];
    sc += __shfl_xor(sc, 1);
    sc += __shfl_xor(sc, 2);
    sc += __shfl_xor(sc, 4);
    // online softmax update
    float mn = fmaxf(m, sc);
    float scale = __expf(m - mn);
    float w = __expf(sc - mn);
    den = den * scale + w;
#pragma unroll
    for (int j = 0; j < VEC; ++j) acc[j] = acc[j] * scale + w * av[j];
    m = mn;
    a_cur = a_next;
  }

  float inv = 1.f / den;
#pragma unroll
  for (int j = 0; j < VEC; ++j) {
    float v = acc[j] * inv;
    // head mean: reduce over lanes stride 8 (same sub-slot, all 8 heads)
    v += __shfl_xor(v, 8);
    v += __shfl_xor(v, 16);
    v += __shfl_xor(v, 32);
    acc[j] = v;
  }

  if (lane < 8) {
    int c0 = lane * VEC;
    if constexpr (L1) {
      bf16* o = out1 + (size_t)node * CH + c0;
#pragma unroll
      for (int j = 0; j < VEC; ++j) {
        float v = acc[j] * 0.125f + bias[c0 + j];
        o[j] = __float2bfloat16(fmaxf(v, 0.f));
      }
    } else {
      float* o = out2 + (size_t)node * CH + c0;
      const float* rs = resid + (size_t)node * CH + c0;
#pragma unroll
      for (int j = 0; j < VEC; ++j)
        o[j] = acc[j] * 0.125f + bias[c0 + j] + rs[j];
    }
  }
}

// ---------------- launch ----------------

extern "C" void kernel_launch(void* const* d_in, const int* in_sizes, int n_in,
                              void* d_out, int out_size, void* d_ws, size_t ws_size,
                              hipStream_t stream) {
  const float* x      = (const float*)d_in[0];
  const int*   ei     = (const int*)d_in[1];
  const float* lin1_w = (const float*)d_in[3];
  const float* lin1_b = (const float*)d_in[4];
  const float* wl1    = (const float*)d_in[5];
  const float* wr1    = (const float*)d_in[6];
  const float* att1   = (const float*)d_in[7];
  const float* b1     = (const float*)d_in[8];
  const float* wl2    = (const float*)d_in[9];
  const float* wr2    = (const float*)d_in[10];
  const float* att2   = (const float*)d_in[11];
  const float* b2     = (const float*)d_in[12];
  float* out = (float*)d_out;

  char* p = (char*)d_ws;
  auto alloc = [&](size_t bytes) {
    char* r = p;
    p += (bytes + 255) & ~size_t(255);
    return r;
  };
  int*   offs  = (int*)alloc((NNODE + 1) * 4);
  int*   deg   = (int*)alloc(NNODE * 4);
  int*   cur   = (int*)alloc(NNODE * 4);
  int*   bsum  = (int*)alloc(SCANB * 4);
  int*   csrc  = (int*)alloc((size_t)NTOT * 4);
  bf16*  xb    = (bf16*)alloc((size_t)NNODE * 128 * 2);
  bf16*  xl    = (bf16*)alloc((size_t)NNODE * 512 * 2);
  bf16*  xr    = (bf16*)alloc((size_t)NNODE * 512 * 2);
  bf16*  h1    = (bf16*)alloc((size_t)NNODE * 64 * 2);
  bf16*  Bp1   = (bf16*)alloc((size_t)128 * 1024 * 2);
  bf16*  Bp2   = (bf16*)alloc((size_t)64 * 512 * 2);
  float* resid = (float*)alloc((size_t)NNODE * 32 * 4);

  (void)hipMemsetAsync(deg, 0, NNODE * 4, stream);
  (void)hipMemsetAsync(cur, 0, NNODE * 4, stream);

  // prep
  k_count<<<(NTOT + 255) / 256, 256, 0, stream>>>(ei, deg);
  k_scan1<<<SCANB, 256, 0, stream>>>(deg, offs, bsum);
  k_scan2<<<1, 256, 0, stream>>>(bsum, SCANB);
  k_scan3<<<SCANB, 256, 0, stream>>>(offs, bsum);
  k_fill<<<(NTOT + 255) / 256, 256, 0, stream>>>(ei, offs, cur, csrc);
  k_cast<<<(NNODE * 128 / 4 + 255) / 256, 256, 0, stream>>>(x, xb, NNODE * 128 / 4);
  k_pack<128, 1024><<<64, 256, 0, stream>>>(wl1, wr1, Bp1);
  k_pack<64, 512><<<16, 256, 0, stream>>>(wl2, wr2, Bp2);
  k_residual<<<NNODE / 8, 256, 0, stream>>>(x, lin1_w, lin1_b, resid, NNODE);

  // layer 1
  k_mfma<128, 1024><<<dim3((NNODE + 31) / 32, 4), 256, 0, stream>>>(xb, Bp1, xl, xr, NNODE);
  k_gat<512, 8, true><<<(NNODE + 3) / 4, 256, 0, stream>>>(xl, xr, att1, csrc, offs, b1, nullptr, h1, nullptr);

  // layer 2
  k_mfma<64, 512><<<dim3((NNODE + 31) / 32, 2), 256, 0, stream>>>(h1, Bp2, xl, xr, NNODE);
  k_gat<256, 4, false><<<(NNODE + 3) / 4, 256, 0, stream>>>(xl, xr, att2, csrc, offs, b2, resid, nullptr, out);
}